// Round 22
// baseline (165.298 us; speedup 1.0000x reference)
//
#include <hip/hip_runtime.h>
#include <math.h>

using f32x4  = __attribute__((ext_vector_type(4))) float;
using bf16x8 = __attribute__((ext_vector_type(8))) short;

constexpr int kB = 4, kC = 256, kL = 2048, kH = 8;
constexpr float kQScale = 0.25505402264f;  // 1/sqrt(32) * log2(e)

__device__ __forceinline__ unsigned short f2bf(float f) {
    unsigned u = __builtin_bit_cast(unsigned, f);
    u += 0x7fffu + ((u >> 16) & 1u);
    return (unsigned short)(u >> 16);
}
__device__ __forceinline__ unsigned cvt_pk(float lo, float hi) {
    unsigned r;
    asm("v_cvt_pk_bf16_f32 %0, %1, %2" : "=v"(r) : "v"(lo), "v"(hi));
    return r;
}
__device__ __forceinline__ f32x4 mfma16(bf16x8 a, bf16x8 b, f32x4 c) {
    return __builtin_amdgcn_mfma_f32_16x16x32_bf16(a, b, c, 0, 0, 0);
}
__device__ __forceinline__ bf16x8 bc8(unsigned a, unsigned b, unsigned c, unsigned d) {
    return __builtin_bit_cast(bf16x8, make_uint4(a, b, c, d));
}
// async global->LDS, 16B per lane; LDS dest = base + lane*16 (HW-linear).
__device__ __forceinline__ void glds16(const unsigned short* g, unsigned short* l) {
    __builtin_amdgcn_global_load_lds(
        (const __attribute__((address_space(1))) unsigned int*)g,
        (__attribute__((address_space(3))) unsigned int*)l, 16, 0, 0);
}

// ---------------------------------------------------------------------------
// Fused GN (blocks 0..127) + weight cvt (blocks 128..383): one launch stage.
// ---------------------------------------------------------------------------
__global__ __launch_bounds__(256) void gncvt_kernel(const float* __restrict__ x,
                                                    const float* __restrict__ gw,
                                                    const float* __restrict__ gb,
                                                    unsigned short* __restrict__ hT,
                                                    const float* __restrict__ qkvw,
                                                    const float* __restrict__ outw,
                                                    unsigned short* __restrict__ wq,
                                                    unsigned short* __restrict__ wo) {
    if (blockIdx.x >= 128) {  // ---- cvt role ----
        int i = (blockIdx.x - 128) * 256 + threadIdx.x;  // 0..65535 float4s
        const float* s; unsigned short* d; int j;
        if (i < 49152) { s = qkvw; d = wq; j = i; }
        else           { s = outw; d = wo; j = i - 49152; }
        float4 v = ((const float4*)s)[j];
        ((uint2*)d)[j] = make_uint2(cvt_pk(v.x, v.y), cvt_pk(v.z, v.w));
        return;
    }
    // ---- groupnorm role ----
    int b = blockIdx.x >> 5, g = blockIdx.x & 31;
    int t = threadIdx.x;
    const float* xp = x + ((size_t)b * kC + g * 8) * kL + 8 * t;

    float v[8][8];
    float s = 0.f, ss = 0.f;
#pragma unroll
    for (int c = 0; c < 8; ++c) {
        float4 a  = *(const float4*)(xp + (size_t)c * kL);
        float4 a2 = *(const float4*)(xp + (size_t)c * kL + 4);
        v[c][0]=a.x; v[c][1]=a.y; v[c][2]=a.z; v[c][3]=a.w;
        v[c][4]=a2.x; v[c][5]=a2.y; v[c][6]=a2.z; v[c][7]=a2.w;
        s  += (a.x+a.y)+(a.z+a.w)+(a2.x+a2.y)+(a2.z+a2.w);
        ss += a.x*a.x+a.y*a.y+a.z*a.z+a.w*a.w+a2.x*a2.x+a2.y*a2.y+a2.z*a2.z+a2.w*a2.w;
    }
#pragma unroll
    for (int off = 32; off; off >>= 1) {
        s  += __shfl_down(s, off);
        ss += __shfl_down(ss, off);
    }
    __shared__ float red[8];
    int wv = t >> 6;
    if ((t & 63) == 0) { red[wv] = s; red[4 + wv] = ss; }
    __syncthreads();
    s  = red[0] + red[1] + red[2] + red[3];
    ss = red[4] + red[5] + red[6] + red[7];
    float mean = s * (1.f / 16384.f);
    float var  = ss * (1.f / 16384.f) - mean * mean;
    float rstd = rsqrtf(var + 1e-5f);

    float wc[8], bc[8];
#pragma unroll
    for (int c = 0; c < 8; ++c) { wc[c] = gw[g*8+c] * rstd; bc[c] = gb[g*8+c]; }

    unsigned short* hp = hT + ((size_t)b * kL + 8 * t) * kC + g * 8;
#pragma unroll
    for (int j = 0; j < 8; ++j) {
        unsigned pk[4];
#pragma unroll
        for (int c2 = 0; c2 < 4; ++c2) {
            pk[c2] = cvt_pk((v[2*c2  ][j] - mean) * wc[2*c2  ] + bc[2*c2  ],
                            (v[2*c2+1][j] - mean) * wc[2*c2+1] + bc[2*c2+1]);
        }
        *(uint4*)(hp + (size_t)j * kC) = make_uint4(pk[0], pk[1], pk[2], pk[3]);
    }
}

// ---------------------------------------------------------------------------
// Merged QKV GEMM v2 (r18, unchanged).
// ---------------------------------------------------------------------------
__device__ __forceinline__ void store_qk(unsigned short* __restrict__ base, size_t bh,
                                         int n, int d0, f32x4 acc,
                                         const float* bias4, float scale) {
    float v0 = (acc[0] + bias4[0]) * scale, v1 = (acc[1] + bias4[1]) * scale;
    float v2 = (acc[2] + bias4[2]) * scale, v3 = (acc[3] + bias4[3]) * scale;
    *(uint2*)(base + (bh * kL + n) * 32 + d0) = make_uint2(cvt_pk(v0, v1), cvt_pk(v2, v3));
}

__global__ __launch_bounds__(256) void qkv_gemm(const unsigned short* __restrict__ Wb,
                                                const unsigned short* __restrict__ hT,
                                                const float* __restrict__ qkvb,
                                                unsigned short* __restrict__ qT,
                                                unsigned short* __restrict__ kT,
                                                unsigned short* __restrict__ vbuf) {
    __shared__ alignas(16) unsigned short Hlds[2][8][512];
    int t = threadIdx.x, wv = t >> 6, ll = t & 15, lg = (t >> 4) & 3;
    int lane = t & 63;
    int n0 = blockIdx.x * 128, o0 = blockIdx.y * 64, b = blockIdx.z;
    int obase = o0 + wv * 16;
    const unsigned short* hb = hT + (size_t)b * kL * kC;

    bf16x8 wf[8];
#pragma unroll
    for (int k = 0; k < 8; ++k)
        wf[k] = *(const bf16x8*)(Wb + (size_t)(obase + ll) * 256 + 32 * k + 8 * lg);
    float bias[4];
#pragma unroll
    for (int r = 0; r < 4; ++r) bias[r] = qkvb[obase + 4 * lg + r];
    int mode = (obase < 256) ? 0 : (obase < 512 ? 1 : 2);
    int d0 = (obase & 31) + 4 * lg;

    const unsigned short* hsrc0 = hb + (size_t)(n0 + 16 * (2 * wv)     + ll) * 256 + 8 * lg;
    const unsigned short* hsrc1 = hb + (size_t)(n0 + 16 * (2 * wv + 1) + ll) * 256 + 8 * lg;

    glds16(hsrc0,      &Hlds[0][2 * wv][0]);
    glds16(hsrc1,      &Hlds[0][2 * wv + 1][0]);
    glds16(hsrc0 + 32, &Hlds[1][2 * wv][0]);
    glds16(hsrc1 + 32, &Hlds[1][2 * wv + 1][0]);
    asm volatile("s_waitcnt vmcnt(2)" ::: "memory");
    __builtin_amdgcn_sched_barrier(0);
    __builtin_amdgcn_s_barrier();

    f32x4 acc[8] = {};
    int cur = 0;
    for (int c = 0; c < 8; ++c) {
        bf16x8 hf[8];
#pragma unroll
        for (int nj = 0; nj < 8; ++nj)
            hf[nj] = *(const bf16x8*)&Hlds[cur][nj][lane * 8];
        asm volatile("s_waitcnt lgkmcnt(0)" ::: "memory");
        __builtin_amdgcn_sched_barrier(0);
        __builtin_amdgcn_s_barrier();

        int kn = ((c + 2) & 7) * 32;
        glds16(hsrc0 + kn, &Hlds[cur][2 * wv][0]);
        glds16(hsrc1 + kn, &Hlds[cur][2 * wv + 1][0]);

        __builtin_amdgcn_s_setprio(1);
#pragma unroll
        for (int nj = 0; nj < 8; ++nj)
            acc[nj] = mfma16(wf[c], hf[nj], acc[nj]);
        __builtin_amdgcn_s_setprio(0);

        asm volatile("s_waitcnt vmcnt(2)" ::: "memory");
        __builtin_amdgcn_sched_barrier(0);
        __builtin_amdgcn_s_barrier();
        cur ^= 1;
    }
    asm volatile("s_waitcnt vmcnt(0)" ::: "memory");

#pragma unroll
    for (int nj = 0; nj < 8; ++nj) {
        int n = n0 + 16 * nj + ll;
        if (mode == 0) {
            store_qk(qT, (size_t)b * kH + (obase >> 5), n, d0, acc[nj], bias, kQScale);
        } else if (mode == 1) {
            store_qk(kT, (size_t)b * kH + ((obase - 256) >> 5), n, d0, acc[nj], bias, 1.f);
        } else {
#pragma unroll
            for (int r = 0; r < 4; ++r) {
                size_t row = (size_t)b * kC + (obase - 512) + 4 * lg + r;
                vbuf[row * kL + n] = f2bf(acc[nj][r] + bias[r]);
            }
        }
    }
}

// ---------------------------------------------------------------------------
// Flash attention v22 = r20 skeleton (K-LDS staging, counted-vmcnt barriers,
// 16 q/wave, 64-q blocks, grid 1024 = 4 blocks/CU, tail-free) with:
//  - LANE-LOCAL P (v5/v6/v7/v11-validated, absmax 0.03125): k-slot<->key map
//    key(e,hi) = 32u + 16*(e>>2) + 4*hi + (e&3); P B-fragment = own cvt_pk
//    words. Deletes the Plds round-trip (32KB/block-iter) + its lgkm chain.
//  - V DIRECT from global in matching layout (8 x uint2, L2-resident),
//    PREFETCHED ONE FULL ITERATION ahead via the r4/r10/r12 in-loop-decl +
//    end-copy idiom (fixes r21's same-iteration exposure).
//  - publish barrier vmcnt(9): 8 nva + 1 fresh glds stay in flight; the
//    previous tile's K glds (older) retires -> next buffer safe.
// lsum add order, key order = r20 verbatim. LDS = Klds only (8 KB).
// ---------------------------------------------------------------------------
__global__ __launch_bounds__(256) void attn_kernel(const unsigned short* __restrict__ qT,
                                                   const unsigned short* __restrict__ kT,
                                                   const unsigned short* __restrict__ vbuf,
                                                   unsigned short* __restrict__ h2T) {
    __shared__ alignas(16) unsigned short Klds[2][4][512];  // [buf][mj][frag order]
    int t = threadIdx.x, wv = t >> 6, ll = t & 15, hi = (t >> 4) & 3;
    int lane = t & 63;
    int j = blockIdx.x;
    int bid = (j & 7) * 128 + (j >> 3);   // XCD swizzle: 1024 = 8 x 128, bijective
    int qg = bid & 31, bh = bid >> 5;     // qg 0..31 (64-q groups), bh 0..31
    int b = bh >> 3, h = bh & 7;
    const unsigned short* qb = qT + (size_t)bh * kL * 32;
    const unsigned short* kb = kT + (size_t)bh * kL * 32;
    const unsigned short* vb = vbuf + ((size_t)b * kC + h * 32) * kL;
    int nq = qg * 64 + wv * 16;           // this wave's 16 queries

    bf16x8 qf = *(const bf16x8*)(qb + (size_t)(nq + ll) * 32 + 8 * hi);

    f32x4 acc[2] = {};                    // [dj]
    float lsum = 0.f;
    const f32x4 zero = {0.f, 0.f, 0.f, 0.f};

    // K staging source (wave stages sub-tile mj = wv)
    const unsigned short* ksrc = kb + (size_t)(16 * wv + ll) * 32 + 8 * hi;
    // V per-lane offsets in the lane-local-P layout: row d, col 4*hi
    const int vo0 = ll * kL + 4 * hi;            // dj=0: d = ll
    const int vo1 = (16 + ll) * kL + 4 * hi;     // dj=1: d = 16+ll

    // prologue: stage K tiles 0,1; load V tile 0 direct
    glds16(ksrc, &Klds[0][wv][0]);
    glds16(ksrc + (size_t)64 * 32, &Klds[1][wv][0]);
    uint2 va[2][2][2];                    // [dj][u][hf]
#pragma unroll
    for (int u = 0; u < 2; ++u)
#pragma unroll
        for (int hf = 0; hf < 2; ++hf) {
            va[0][u][hf] = *(const uint2*)(vb + vo0 + 32 * u + 16 * hf);
            va[1][u][hf] = *(const uint2*)(vb + vo1 + 32 * u + 16 * hf);
        }
    asm volatile("s_waitcnt vmcnt(9)" ::: "memory");  // K tile 0 retired
    __builtin_amdgcn_sched_barrier(0);
    __builtin_amdgcn_s_barrier();

    int cur = 0;
    for (int it = 0; it < 32; ++it) {
        // A: K fragments from LDS (conflict-free b128) + prefetch V tile it+1
        bf16x8 ka[4];
#pragma unroll
        for (int mj = 0; mj < 4; ++mj)
            ka[mj] = *(const bf16x8*)&Klds[cur][mj][lane * 8];
        int mn = ((it + 1) & 31) * 64;    // wraps harmlessly on last iter
        uint2 nva[2][2][2];
#pragma unroll
        for (int u = 0; u < 2; ++u)
#pragma unroll
            for (int hf = 0; hf < 2; ++hf) {
                nva[0][u][hf] = *(const uint2*)(vb + vo0 + mn + 32 * u + 16 * hf);
                nva[1][u][hf] = *(const uint2*)(vb + vo1 + mn + 32 * u + 16 * hf);
            }

        // B: read-barrier -> Klds[cur] may be overwritten
        asm volatile("s_waitcnt lgkmcnt(0)" ::: "memory");
        __builtin_amdgcn_sched_barrier(0);
        __builtin_amdgcn_s_barrier();

        // C: stage K tile it+2 into buf[cur]
        int kn = ((it + 2) & 31) * 64;
        glds16(ksrc + (size_t)kn * 32, &Klds[cur][wv][0]);

        // D: QK^T (swapped), exp2 -> lane-local P (registers only), PV
        f32x4 s[4];
        __builtin_amdgcn_s_setprio(1);
#pragma unroll
        for (int mj = 0; mj < 4; ++mj)
            s[mj] = mfma16(ka[mj], qf, zero);
        __builtin_amdgcn_s_setprio(0);

        unsigned w[4][2];
#pragma unroll
        for (int mj = 0; mj < 4; ++mj) {
            float p0 = __builtin_amdgcn_exp2f(s[mj][0]);
            float p1 = __builtin_amdgcn_exp2f(s[mj][1]);
            float p2 = __builtin_amdgcn_exp2f(s[mj][2]);
            float p3 = __builtin_amdgcn_exp2f(s[mj][3]);
            lsum += (p0 + p1) + (p2 + p3);
            w[mj][0] = cvt_pk(p0, p1);
            w[mj][1] = cvt_pk(p2, p3);
        }

        __builtin_amdgcn_s_setprio(1);
#pragma unroll
        for (int u = 0; u < 2; ++u) {
            bf16x8 pb  = bc8(w[2*u][0], w[2*u][1], w[2*u+1][0], w[2*u+1][1]);
            bf16x8 va0 = bc8(va[0][u][0].x, va[0][u][0].y, va[0][u][1].x, va[0][u][1].y);
            bf16x8 va1 = bc8(va[1][u][0].x, va[1][u][0].y, va[1][u][1].x, va[1][u][1].y);
            acc[0] = mfma16(va0, pb, acc[0]);
            acc[1] = mfma16(va1, pb, acc[1]);
        }
        __builtin_amdgcn_s_setprio(0);

        // E: publish-barrier; vmcnt(9) keeps nva(8)+glds(1) in flight, retires
        //    the previous tile's K glds -> next buffer safe for all waves.
        asm volatile("s_waitcnt vmcnt(9)" ::: "memory");
        __builtin_amdgcn_sched_barrier(0);
        __builtin_amdgcn_s_barrier();

        // copy prefetched V (r4 idiom; compiler waits nva here, ~full iter after issue)
#pragma unroll
        for (int dj = 0; dj < 2; ++dj)
#pragma unroll
            for (int u = 0; u < 2; ++u)
#pragma unroll
                for (int hf = 0; hf < 2; ++hf) va[dj][u][hf] = nva[dj][u][hf];
        cur ^= 1;
    }
    asm volatile("s_waitcnt vmcnt(0)" ::: "memory");  // retire wrapped dummy stages

    lsum += __shfl_xor(lsum, 16);
    lsum += __shfl_xor(lsum, 32);
    float inv = 1.f / lsum;
    unsigned short* ob = h2T + ((size_t)b * kL + nq + ll) * kC + h * 32;
    *(uint2*)(ob + 4 * hi)      = make_uint2(cvt_pk(acc[0][0] * inv, acc[0][1] * inv),
                                             cvt_pk(acc[0][2] * inv, acc[0][3] * inv));
    *(uint2*)(ob + 16 + 4 * hi) = make_uint2(cvt_pk(acc[1][0] * inv, acc[1][1] * inv),
                                             cvt_pk(acc[1][2] * inv, acc[1][3] * inv));
}

// ---------------------------------------------------------------------------
// OUT GEMM v2 (r18, unchanged): staged-B pipeline, bias+residual, fp32 out.
// ---------------------------------------------------------------------------
__global__ __launch_bounds__(256) void out_gemm(const unsigned short* __restrict__ Wb,
                                                const unsigned short* __restrict__ h2T,
                                                const float* __restrict__ outb,
                                                const float* __restrict__ x,
                                                float* __restrict__ out) {
    __shared__ alignas(16) unsigned short Hlds[2][8][512];
    int t = threadIdx.x, wv = t >> 6, ll = t & 15, lg = (t >> 4) & 3;
    int lane = t & 63;
    int n0 = blockIdx.x * 128, o0 = blockIdx.y * 64, b = blockIdx.z;
    int obase = o0 + wv * 16;
    const unsigned short* hb = h2T + (size_t)b * kL * kC;

    bf16x8 wf[8];
#pragma unroll
    for (int k = 0; k < 8; ++k)
        wf[k] = *(const bf16x8*)(Wb + (size_t)(obase + ll) * 256 + 32 * k + 8 * lg);
    float bias[4];
#pragma unroll
    for (int r = 0; r < 4; ++r) bias[r] = outb[obase + 4 * lg + r];

    const unsigned short* hsrc0 = hb + (size_t)(n0 + 16 * (2 * wv)     + ll) * 256 + 8 * lg;
    const unsigned short* hsrc1 = hb + (size_t)(n0 + 16 * (2 * wv + 1) + ll) * 256 + 8 * lg;

    glds16(hsrc0,      &Hlds[0][2 * wv][0]);
    glds16(hsrc1,      &Hlds[0][2 * wv + 1][0]);
    glds16(hsrc0 + 32, &Hlds[1][2 * wv][0]);
    glds16(hsrc1 + 32, &Hlds[1][2 * wv + 1][0]);
    asm volatile("s_waitcnt vmcnt(2)" ::: "memory");
    __builtin_amdgcn_sched_barrier(0);
    __builtin_amdgcn_s_barrier();

    f32x4 acc[8] = {};
    int cur = 0;
    for (int c = 0; c < 8; ++c) {
        bf16x8 hf[8];
#pragma unroll
        for (int nj = 0; nj < 8; ++nj)
            hf[nj] = *(const bf16x8*)&Hlds[cur][nj][lane * 8];
        asm volatile("s_waitcnt lgkmcnt(0)" ::: "memory");
        __builtin_amdgcn_sched_barrier(0);
        __builtin_amdgcn_s_barrier();

        int kn = ((c + 2) & 7) * 32;
        glds16(hsrc0 + kn, &Hlds[cur][2 * wv][0]);
        glds16(hsrc1 + kn, &Hlds[cur][2 * wv + 1][0]);

        __builtin_amdgcn_s_setprio(1);
#pragma unroll
        for (int nj = 0; nj < 8; ++nj)
            acc[nj] = mfma16(wf[c], hf[nj], acc[nj]);
        __builtin_amdgcn_s_setprio(0);

        asm volatile("s_waitcnt vmcnt(2)" ::: "memory");
        __builtin_amdgcn_sched_barrier(0);
        __builtin_amdgcn_s_barrier();
        cur ^= 1;
    }
    asm volatile("s_waitcnt vmcnt(0)" ::: "memory");

#pragma unroll
    for (int nj = 0; nj < 8; ++nj) {
        int n = n0 + 16 * nj + ll;
#pragma unroll
        for (int r = 0; r < 4; ++r) {
            size_t row = (size_t)b * kC + obase + 4 * lg + r;
            out[row * kL + n] = acc[nj][r] + bias[r] + x[row * kL + n];
        }
    }
}

// ---------------------------------------------------------------------------
extern "C" void kernel_launch(void* const* d_in, const int* in_sizes, int n_in,
                              void* d_out, int out_size, void* d_ws, size_t ws_size,
                              hipStream_t stream) {
    const float* x     = (const float*)d_in[0];
    const float* gn_w  = (const float*)d_in[1];
    const float* gn_b  = (const float*)d_in[2];
    const float* qkv_w = (const float*)d_in[3];
    const float* qkv_b = (const float*)d_in[4];
    const float* out_w = (const float*)d_in[5];
    const float* out_b = (const float*)d_in[6];
    float* out = (float*)d_out;

    char* ws = (char*)d_ws;
    const size_t MB = 1024 * 1024;
    unsigned short* hT   = (unsigned short*)(ws);             // 0-4 MB
    unsigned short* qT   = (unsigned short*)(ws + 4  * MB);   // 4-8 MB
    unsigned short* kT   = (unsigned short*)(ws + 8  * MB);   // 8-12 MB
    unsigned short* vbuf = (unsigned short*)(ws + 12 * MB);   // 12-16 MB
    unsigned short* h2T  = (unsigned short*)(ws + 16 * MB);   // 16-20 MB
    unsigned short* wqkv = (unsigned short*)(ws + 20 * MB);   // 20-20.375 MB
    unsigned short* wout = (unsigned short*)(ws + 20 * MB + 512 * 1024);

    gncvt_kernel<<<dim3(384), 256, 0, stream>>>(x, gn_w, gn_b, hT, qkv_w, out_w, wqkv, wout);
    qkv_gemm<<<dim3(16, 12, kB), 256, 0, stream>>>(wqkv, hT, qkv_b, qT, kT, vbuf);
    attn_kernel<<<dim3(1024), 256, 0, stream>>>(qT, kT, vbuf, h2T);
    out_gemm<<<dim3(16, 4, kB), 256, 0, stream>>>(wout, h2T, out_b, x, out);
}

// Round 23
// 70.922 us; speedup vs baseline: 2.3307x; 2.3307x over previous
//
#include <hip/hip_runtime.h>
#include <math.h>

using f32x4  = __attribute__((ext_vector_type(4))) float;
using bf16x8 = __attribute__((ext_vector_type(8))) short;

constexpr int kB = 4, kC = 256, kL = 2048, kH = 8;
constexpr float kQScale = 0.25505402264f;  // 1/sqrt(32) * log2(e)

__device__ __forceinline__ unsigned short f2bf(float f) {
    unsigned u = __builtin_bit_cast(unsigned, f);
    u += 0x7fffu + ((u >> 16) & 1u);
    return (unsigned short)(u >> 16);
}
__device__ __forceinline__ unsigned cvt_pk(float lo, float hi) {
    unsigned r;
    asm("v_cvt_pk_bf16_f32 %0, %1, %2" : "=v"(r) : "v"(lo), "v"(hi));
    return r;
}
__device__ __forceinline__ f32x4 mfma16(bf16x8 a, bf16x8 b, f32x4 c) {
    return __builtin_amdgcn_mfma_f32_16x16x32_bf16(a, b, c, 0, 0, 0);
}
__device__ __forceinline__ bf16x8 bc8(unsigned a, unsigned b, unsigned c, unsigned d) {
    return __builtin_bit_cast(bf16x8, make_uint4(a, b, c, d));
}
// async global->LDS, 16B per lane; LDS dest = base + lane*16 (HW-linear).
__device__ __forceinline__ void glds16(const unsigned short* g, unsigned short* l) {
    __builtin_amdgcn_global_load_lds(
        (const __attribute__((address_space(1))) unsigned int*)g,
        (__attribute__((address_space(3))) unsigned int*)l, 16, 0, 0);
}

// ---------------------------------------------------------------------------
// Fused GN (blocks 0..127) + weight cvt (blocks 128..383): one launch stage.
// ---------------------------------------------------------------------------
__global__ __launch_bounds__(256) void gncvt_kernel(const float* __restrict__ x,
                                                    const float* __restrict__ gw,
                                                    const float* __restrict__ gb,
                                                    unsigned short* __restrict__ hT,
                                                    const float* __restrict__ qkvw,
                                                    const float* __restrict__ outw,
                                                    unsigned short* __restrict__ wq,
                                                    unsigned short* __restrict__ wo) {
    if (blockIdx.x >= 128) {  // ---- cvt role ----
        int i = (blockIdx.x - 128) * 256 + threadIdx.x;  // 0..65535 float4s
        const float* s; unsigned short* d; int j;
        if (i < 49152) { s = qkvw; d = wq; j = i; }
        else           { s = outw; d = wo; j = i - 49152; }
        float4 v = ((const float4*)s)[j];
        ((uint2*)d)[j] = make_uint2(cvt_pk(v.x, v.y), cvt_pk(v.z, v.w));
        return;
    }
    // ---- groupnorm role ----
    int b = blockIdx.x >> 5, g = blockIdx.x & 31;
    int t = threadIdx.x;
    const float* xp = x + ((size_t)b * kC + g * 8) * kL + 8 * t;

    float v[8][8];
    float s = 0.f, ss = 0.f;
#pragma unroll
    for (int c = 0; c < 8; ++c) {
        float4 a  = *(const float4*)(xp + (size_t)c * kL);
        float4 a2 = *(const float4*)(xp + (size_t)c * kL + 4);
        v[c][0]=a.x; v[c][1]=a.y; v[c][2]=a.z; v[c][3]=a.w;
        v[c][4]=a2.x; v[c][5]=a2.y; v[c][6]=a2.z; v[c][7]=a2.w;
        s  += (a.x+a.y)+(a.z+a.w)+(a2.x+a2.y)+(a2.z+a2.w);
        ss += a.x*a.x+a.y*a.y+a.z*a.z+a.w*a.w+a2.x*a2.x+a2.y*a2.y+a2.z*a2.z+a2.w*a2.w;
    }
#pragma unroll
    for (int off = 32; off; off >>= 1) {
        s  += __shfl_down(s, off);
        ss += __shfl_down(ss, off);
    }
    __shared__ float red[8];
    int wv = t >> 6;
    if ((t & 63) == 0) { red[wv] = s; red[4 + wv] = ss; }
    __syncthreads();
    s  = red[0] + red[1] + red[2] + red[3];
    ss = red[4] + red[5] + red[6] + red[7];
    float mean = s * (1.f / 16384.f);
    float var  = ss * (1.f / 16384.f) - mean * mean;
    float rstd = rsqrtf(var + 1e-5f);

    float wc[8], bc[8];
#pragma unroll
    for (int c = 0; c < 8; ++c) { wc[c] = gw[g*8+c] * rstd; bc[c] = gb[g*8+c]; }

    unsigned short* hp = hT + ((size_t)b * kL + 8 * t) * kC + g * 8;
#pragma unroll
    for (int j = 0; j < 8; ++j) {
        unsigned pk[4];
#pragma unroll
        for (int c2 = 0; c2 < 4; ++c2) {
            pk[c2] = cvt_pk((v[2*c2  ][j] - mean) * wc[2*c2  ] + bc[2*c2  ],
                            (v[2*c2+1][j] - mean) * wc[2*c2+1] + bc[2*c2+1]);
        }
        *(uint4*)(hp + (size_t)j * kC) = make_uint4(pk[0], pk[1], pk[2], pk[3]);
    }
}

// ---------------------------------------------------------------------------
// Merged QKV GEMM v2 (r18/r20, unchanged): W-in-registers + LDS-staged B
// shared by all 4 waves, counted-vmcnt barriers.
// ---------------------------------------------------------------------------
__device__ __forceinline__ void store_qk(unsigned short* __restrict__ base, size_t bh,
                                         int n, int d0, f32x4 acc,
                                         const float* bias4, float scale) {
    float v0 = (acc[0] + bias4[0]) * scale, v1 = (acc[1] + bias4[1]) * scale;
    float v2 = (acc[2] + bias4[2]) * scale, v3 = (acc[3] + bias4[3]) * scale;
    *(uint2*)(base + (bh * kL + n) * 32 + d0) = make_uint2(cvt_pk(v0, v1), cvt_pk(v2, v3));
}

__global__ __launch_bounds__(256) void qkv_gemm(const unsigned short* __restrict__ Wb,
                                                const unsigned short* __restrict__ hT,
                                                const float* __restrict__ qkvb,
                                                unsigned short* __restrict__ qT,
                                                unsigned short* __restrict__ kT,
                                                unsigned short* __restrict__ vbuf) {
    __shared__ alignas(16) unsigned short Hlds[2][8][512];
    int t = threadIdx.x, wv = t >> 6, ll = t & 15, lg = (t >> 4) & 3;
    int lane = t & 63;
    int n0 = blockIdx.x * 128, o0 = blockIdx.y * 64, b = blockIdx.z;
    int obase = o0 + wv * 16;
    const unsigned short* hb = hT + (size_t)b * kL * kC;

    bf16x8 wf[8];
#pragma unroll
    for (int k = 0; k < 8; ++k)
        wf[k] = *(const bf16x8*)(Wb + (size_t)(obase + ll) * 256 + 32 * k + 8 * lg);
    float bias[4];
#pragma unroll
    for (int r = 0; r < 4; ++r) bias[r] = qkvb[obase + 4 * lg + r];
    int mode = (obase < 256) ? 0 : (obase < 512 ? 1 : 2);
    int d0 = (obase & 31) + 4 * lg;

    const unsigned short* hsrc0 = hb + (size_t)(n0 + 16 * (2 * wv)     + ll) * 256 + 8 * lg;
    const unsigned short* hsrc1 = hb + (size_t)(n0 + 16 * (2 * wv + 1) + ll) * 256 + 8 * lg;

    glds16(hsrc0,      &Hlds[0][2 * wv][0]);
    glds16(hsrc1,      &Hlds[0][2 * wv + 1][0]);
    glds16(hsrc0 + 32, &Hlds[1][2 * wv][0]);
    glds16(hsrc1 + 32, &Hlds[1][2 * wv + 1][0]);
    asm volatile("s_waitcnt vmcnt(2)" ::: "memory");
    __builtin_amdgcn_sched_barrier(0);
    __builtin_amdgcn_s_barrier();

    f32x4 acc[8] = {};
    int cur = 0;
    for (int c = 0; c < 8; ++c) {
        bf16x8 hf[8];
#pragma unroll
        for (int nj = 0; nj < 8; ++nj)
            hf[nj] = *(const bf16x8*)&Hlds[cur][nj][lane * 8];
        asm volatile("s_waitcnt lgkmcnt(0)" ::: "memory");
        __builtin_amdgcn_sched_barrier(0);
        __builtin_amdgcn_s_barrier();

        int kn = ((c + 2) & 7) * 32;
        glds16(hsrc0 + kn, &Hlds[cur][2 * wv][0]);
        glds16(hsrc1 + kn, &Hlds[cur][2 * wv + 1][0]);

        __builtin_amdgcn_s_setprio(1);
#pragma unroll
        for (int nj = 0; nj < 8; ++nj)
            acc[nj] = mfma16(wf[c], hf[nj], acc[nj]);
        __builtin_amdgcn_s_setprio(0);

        asm volatile("s_waitcnt vmcnt(2)" ::: "memory");
        __builtin_amdgcn_sched_barrier(0);
        __builtin_amdgcn_s_barrier();
        cur ^= 1;
    }
    asm volatile("s_waitcnt vmcnt(0)" ::: "memory");

#pragma unroll
    for (int nj = 0; nj < 8; ++nj) {
        int n = n0 + 16 * nj + ll;
        if (mode == 0) {
            store_qk(qT, (size_t)b * kH + (obase >> 5), n, d0, acc[nj], bias, kQScale);
        } else if (mode == 1) {
            store_qk(kT, (size_t)b * kH + ((obase - 256) >> 5), n, d0, acc[nj], bias, 1.f);
        } else {
#pragma unroll
            for (int r = 0; r < 4; ++r) {
                size_t row = (size_t)b * kC + (obase - 512) + 4 * lg + r;
                vbuf[row * kL + n] = f2bf(acc[nj][r] + bias[r]);
            }
        }
    }
}

// ---------------------------------------------------------------------------
// Flash attention v20 (r20 VERBATIM — best attn: 41.0us, absmax 0.03125).
// 16 q/wave, 64-q blocks, grid 1024 = 4 blocks/CU; K+V staged in LDS via
// glds16; counted-vmcnt raw barriers; lsum fp32 + shfl reduce.
// ---------------------------------------------------------------------------
__global__ __launch_bounds__(256) void attn_kernel(const unsigned short* __restrict__ qT,
                                                   const unsigned short* __restrict__ kT,
                                                   const unsigned short* __restrict__ vbuf,
                                                   unsigned short* __restrict__ h2T) {
    __shared__ alignas(16) unsigned short Klds[2][4][512];  // [buf][mj][frag order]
    __shared__ alignas(16) unsigned short Vlds[2][4][512];  // [buf][dj*2+tt][frag]
    __shared__ unsigned Plds[4][16][34];
    int t = threadIdx.x, wv = t >> 6, ll = t & 15, hi = (t >> 4) & 3;
    int lane = t & 63;
    int j = blockIdx.x;
    int bid = (j & 7) * 128 + (j >> 3);   // XCD swizzle: 1024 = 8 x 128, bijective
    int qg = bid & 31, bh = bid >> 5;     // qg 0..31 (64-q groups), bh 0..31
    int b = bh >> 3, h = bh & 7;
    const unsigned short* qb = qT + (size_t)bh * kL * 32;
    const unsigned short* kb = kT + (size_t)bh * kL * 32;
    const unsigned short* vb = vbuf + ((size_t)b * kC + h * 32) * kL;
    int nq = qg * 64 + wv * 16;           // this wave's 16 queries

    bf16x8 qf = *(const bf16x8*)(qb + (size_t)(nq + ll) * 32 + 8 * hi);

    f32x4 acc[2] = {};                    // [dj]
    float lsum = 0.f;
    const f32x4 zero = {0.f, 0.f, 0.f, 0.f};

    // staging assignments: wave stages K sub-tile mj=wv and V sub-tile
    // (dj,tt) = (wv>>1, wv&1); 1KB wave-wide glds16 each.
    const unsigned short* ksrc = kb + (size_t)(16 * wv + ll) * 32 + 8 * hi;
    const unsigned short* vsrc = vb + (size_t)(16 * (wv >> 1) + ll) * kL + 32 * (wv & 1) + 8 * hi;

    // prologue: stage tiles 0 and 1
    glds16(ksrc, &Klds[0][wv][0]);
    glds16(vsrc, &Vlds[0][wv][0]);
    glds16(ksrc + (size_t)64 * 32, &Klds[1][wv][0]);
    glds16(vsrc + 64,              &Vlds[1][wv][0]);
    asm volatile("s_waitcnt vmcnt(2)" ::: "memory");
    __builtin_amdgcn_sched_barrier(0);
    __builtin_amdgcn_s_barrier();

    int cur = 0;
    for (int it = 0; it < 32; ++it) {
        // A: read tile-it fragments (conflict-free b128)
        bf16x8 ka[4], va[2][2];
#pragma unroll
        for (int mj = 0; mj < 4; ++mj)
            ka[mj] = *(const bf16x8*)&Klds[cur][mj][lane * 8];
#pragma unroll
        for (int dj = 0; dj < 2; ++dj)
#pragma unroll
            for (int tt = 0; tt < 2; ++tt)
                va[dj][tt] = *(const bf16x8*)&Vlds[cur][dj * 2 + tt][lane * 8];

        // B: read-barrier -> buf[cur] may be overwritten
        asm volatile("s_waitcnt lgkmcnt(0)" ::: "memory");
        __builtin_amdgcn_sched_barrier(0);
        __builtin_amdgcn_s_barrier();

        // C: stage tile it+2 into buf[cur] (wraps harmlessly on last 2 iters)
        int kn = ((it + 2) & 31) * 64;
        glds16(ksrc + (size_t)kn * 32, &Klds[cur][wv][0]);
        glds16(vsrc + kn,              &Vlds[cur][wv][0]);

        // D: compute — QK^T: s[mj] = S^T[key 64it+16mj+4hi+r][query nq+ll]
        f32x4 s[4];
        __builtin_amdgcn_s_setprio(1);
#pragma unroll
        for (int mj = 0; mj < 4; ++mj)
            s[mj] = mfma16(ka[mj], qf, zero);
        __builtin_amdgcn_s_setprio(0);

#pragma unroll
        for (int mj = 0; mj < 4; ++mj) {
            float p0 = __builtin_amdgcn_exp2f(s[mj][0]);
            float p1 = __builtin_amdgcn_exp2f(s[mj][1]);
            float p2 = __builtin_amdgcn_exp2f(s[mj][2]);
            float p3 = __builtin_amdgcn_exp2f(s[mj][3]);
            lsum += (p0 + p1) + (p2 + p3);
            *(uint2*)&Plds[wv][ll][8 * mj + 2 * hi] =
                make_uint2(cvt_pk(p0, p1), cvt_pk(p2, p3));
        }

        // read P as B-fragments: pbf[tt] = P[keys 32tt+8hi..+7][query ll]
        bf16x8 pbf[2];
#pragma unroll
        for (int tt = 0; tt < 2; ++tt) {
            uint2 lo  = *(uint2*)&Plds[wv][ll][16 * tt + 4 * hi];
            uint2 hi2 = *(uint2*)&Plds[wv][ll][16 * tt + 4 * hi + 2];
            pbf[tt] = bc8(lo.x, lo.y, hi2.x, hi2.y);
        }

        __builtin_amdgcn_s_setprio(1);
#pragma unroll
        for (int tt = 0; tt < 2; ++tt)
#pragma unroll
            for (int dj = 0; dj < 2; ++dj)
                acc[dj] = mfma16(va[dj][tt], pbf[tt], acc[dj]);
        __builtin_amdgcn_s_setprio(0);

        // E: publish-barrier, counted vmcnt (tile it+1 retired; it+2 in flight)
        asm volatile("s_waitcnt vmcnt(2)" ::: "memory");
        __builtin_amdgcn_sched_barrier(0);
        __builtin_amdgcn_s_barrier();
        cur ^= 1;
    }
    asm volatile("s_waitcnt vmcnt(0)" ::: "memory");  // retire wrapped dummy stages

    lsum += __shfl_xor(lsum, 16);
    lsum += __shfl_xor(lsum, 32);
    float inv = 1.f / lsum;
    unsigned short* ob = h2T + ((size_t)b * kL + nq + ll) * kC + h * 32;
    *(uint2*)(ob + 4 * hi)      = make_uint2(cvt_pk(acc[0][0] * inv, acc[0][1] * inv),
                                             cvt_pk(acc[0][2] * inv, acc[0][3] * inv));
    *(uint2*)(ob + 16 + 4 * hi) = make_uint2(cvt_pk(acc[1][0] * inv, acc[1][1] * inv),
                                             cvt_pk(acc[1][2] * inv, acc[1][3] * inv));
}

// ---------------------------------------------------------------------------
// OUT GEMM v3: staged-B counted-vmcnt pipeline at n-tile 64 -> grid 512 =
// 2 blocks/CU (was 1/CU at n-tile 128). Per-output k-accumulation order
// unchanged (ascending k, same adds) -> bit-identical results.
// Wave stages 1 sub-tile per chunk (nj = wv); vmcnt(1) keeps the next
// chunk's stage in flight across the publish barrier.
// ---------------------------------------------------------------------------
__global__ __launch_bounds__(256) void out_gemm(const unsigned short* __restrict__ Wb,
                                                const unsigned short* __restrict__ h2T,
                                                const float* __restrict__ outb,
                                                const float* __restrict__ x,
                                                float* __restrict__ out) {
    __shared__ alignas(16) unsigned short Hlds[2][4][512];
    int t = threadIdx.x, wv = t >> 6, ll = t & 15, lg = (t >> 4) & 3;
    int lane = t & 63;
    int n0 = blockIdx.x * 64, o0 = blockIdx.y * 64, b = blockIdx.z;
    int obase = o0 + wv * 16;
    const unsigned short* hb = h2T + (size_t)b * kL * kC;

    bf16x8 wf[8];
#pragma unroll
    for (int k = 0; k < 8; ++k)
        wf[k] = *(const bf16x8*)(Wb + (size_t)(obase + ll) * 256 + 32 * k + 8 * lg);
    float bias[4];
#pragma unroll
    for (int r = 0; r < 4; ++r) bias[r] = outb[obase + 4 * lg + r];

    // staging source: wave stages sub-tile nj = wv
    const unsigned short* hsrc = hb + (size_t)(n0 + 16 * wv + ll) * 256 + 8 * lg;

    glds16(hsrc,      &Hlds[0][wv][0]);
    glds16(hsrc + 32, &Hlds[1][wv][0]);
    asm volatile("s_waitcnt vmcnt(1)" ::: "memory");
    __builtin_amdgcn_sched_barrier(0);
    __builtin_amdgcn_s_barrier();

    f32x4 acc[4] = {};
    int cur = 0;
    for (int c = 0; c < 8; ++c) {
        bf16x8 hf[4];
#pragma unroll
        for (int nj = 0; nj < 4; ++nj)
            hf[nj] = *(const bf16x8*)&Hlds[cur][nj][lane * 8];
        asm volatile("s_waitcnt lgkmcnt(0)" ::: "memory");
        __builtin_amdgcn_sched_barrier(0);
        __builtin_amdgcn_s_barrier();

        int kn = ((c + 2) & 7) * 32;   // wrapped dummy stage on last 2 chunks
        glds16(hsrc + kn, &Hlds[cur][wv][0]);

        __builtin_amdgcn_s_setprio(1);
#pragma unroll
        for (int nj = 0; nj < 4; ++nj)
            acc[nj] = mfma16(wf[c], hf[nj], acc[nj]);
        __builtin_amdgcn_s_setprio(0);

        asm volatile("s_waitcnt vmcnt(1)" ::: "memory");
        __builtin_amdgcn_sched_barrier(0);
        __builtin_amdgcn_s_barrier();
        cur ^= 1;
    }
    asm volatile("s_waitcnt vmcnt(0)" ::: "memory");

#pragma unroll
    for (int nj = 0; nj < 4; ++nj) {
        int n = n0 + 16 * nj + ll;
#pragma unroll
        for (int r = 0; r < 4; ++r) {
            size_t row = (size_t)b * kC + obase + 4 * lg + r;
            out[row * kL + n] = acc[nj][r] + bias[r] + x[row * kL + n];
        }
    }
}

// ---------------------------------------------------------------------------
extern "C" void kernel_launch(void* const* d_in, const int* in_sizes, int n_in,
                              void* d_out, int out_size, void* d_ws, size_t ws_size,
                              hipStream_t stream) {
    const float* x     = (const float*)d_in[0];
    const float* gn_w  = (const float*)d_in[1];
    const float* gn_b  = (const float*)d_in[2];
    const float* qkv_w = (const float*)d_in[3];
    const float* qkv_b = (const float*)d_in[4];
    const float* out_w = (const float*)d_in[5];
    const float* out_b = (const float*)d_in[6];
    float* out = (float*)d_out;

    char* ws = (char*)d_ws;
    const size_t MB = 1024 * 1024;
    unsigned short* hT   = (unsigned short*)(ws);             // 0-4 MB
    unsigned short* qT   = (unsigned short*)(ws + 4  * MB);   // 4-8 MB
    unsigned short* kT   = (unsigned short*)(ws + 8  * MB);   // 8-12 MB
    unsigned short* vbuf = (unsigned short*)(ws + 12 * MB);   // 12-16 MB
    unsigned short* h2T  = (unsigned short*)(ws + 16 * MB);   // 16-20 MB
    unsigned short* wqkv = (unsigned short*)(ws + 20 * MB);   // 20-20.375 MB
    unsigned short* wout = (unsigned short*)(ws + 20 * MB + 512 * 1024);

    gncvt_kernel<<<dim3(384), 256, 0, stream>>>(x, gn_w, gn_b, hT, qkv_w, out_w, wqkv, wout);
    qkv_gemm<<<dim3(16, 12, kB), 256, 0, stream>>>(wqkv, hT, qkv_b, qT, kT, vbuf);
    attn_kernel<<<dim3(1024), 256, 0, stream>>>(qT, kT, vbuf, h2T);
    out_gemm<<<dim3(32, 4, kB), 256, 0, stream>>>(wout, h2T, out_b, x, out);
}